// Round 14
// baseline (176.435 us; speedup 1.0000x reference)
//
#include <hip/hip_runtime.h>
#include <hip/hip_bf16.h>
#include <math.h>
#include <limits.h>

typedef __hip_bfloat16 bf16;
typedef __bf16 bf16x8 __attribute__((ext_vector_type(8)));
typedef float  f32x4  __attribute__((ext_vector_type(4)));

#define DEVI __device__ __forceinline__

static constexpr int Bb     = 2;
static constexpr int Ss     = 2048;
static constexpr int DMODEL = 1024;
static constexpr int NTOK   = Bb * Ss;   // 4096

DEVI float bf2f(bf16 v) { return __bfloat162float(v); }
DEVI bf16  f2bf(float v) { return __float2bfloat16(v); }

DEVI unsigned int packbf(float lo, float hi) {
  union { bf16 b; unsigned short u; } a, c;
  a.b = f2bf(lo); c.b = f2bf(hi);
  return ((unsigned int)c.u << 16) | a.u;
}
DEVI float bfu2f(unsigned short u) {
  unsigned int x = (unsigned int)u << 16;
  float f; __builtin_memcpy(&f, &x, 4); return f;
}

DEVI void async_load16(const bf16* g, bf16* l) {
  __builtin_amdgcn_global_load_lds((const __attribute__((address_space(1))) void*)g,
                                   (__attribute__((address_space(3))) void*)l, 16, 0, 0);
}

// ---------------------------------------------------------------- transpose(+add) + convert + bias-sum
struct TransDesc { const float* src; const float* src2; bf16* dst; int R; int C; int tstart; };
struct TransPack { TransDesc d[8]; };

__global__ __launch_bounds__(256) void trans_conv_kernel(
    TransPack p, const float* __restrict__ cx, bf16* __restrict__ cxo, int tstartConv,
    const float* __restrict__ ba1, const float* __restrict__ ba2,
    float* __restrict__ bsum, int tstartB) {
  __shared__ bf16 tl[64][65];
  const int t = blockIdx.x;
  if (t >= tstartB) {
    const int j = (t - tstartB) * 256 + threadIdx.x;
    bsum[j] = ba1[j] + ba2[j];
    return;
  }
  if (t >= tstartConv) {
    const int idx = (t - tstartConv) * 256 + threadIdx.x;
    const float4 v = ((const float4*)cx)[idx];
    uint2 o; o.x = packbf(v.x, v.y); o.y = packbf(v.z, v.w);
    *(uint2*)&cxo[(size_t)idx * 4] = o;
    return;
  }
  int i = 0;
#pragma unroll
  for (int j = 1; j < 8; ++j) if (t >= p.d[j].tstart) i = j;
  const float* __restrict__ in  = p.d[i].src;
  const float* __restrict__ in2 = p.d[i].src2;
  bf16* __restrict__ out = p.d[i].dst;
  const int R = p.d[i].R, C = p.d[i].C;
  const int rel = t - p.d[i].tstart;
  const int tilesC = C >> 6;
  const int r0 = (rel / tilesC) * 64, c0 = (rel % tilesC) * 64;
  const int tc = threadIdx.x & 63, tr = threadIdx.x >> 6;
#pragma unroll
  for (int q = 0; q < 16; ++q) {
    int r = tr + q * 4;
    float v = in[(size_t)(r0 + r) * C + c0 + tc];
    if (in2) v += in2[(size_t)(r0 + r) * C + c0 + tc];
    tl[r][tc] = f2bf(v);
  }
  __syncthreads();
#pragma unroll
  for (int q = 0; q < 16; ++q) {
    int r = tr + q * 4;
    out[(size_t)(c0 + r) * R + r0 + tc] = tl[tc][r];
  }
}

// ---------------------------------------------------------------- batched GEMM (+optional in-place Kr-add)
struct GemmDesc {
  const bf16* A; const bf16* WT; const float* b1; const float* b2; const bf16* addm; bf16* C;
  int lda, ldb, ldc, K, bsplit, nTX, blkStart, biasRow;
};
struct GemmBatch { GemmDesc d[4]; };

__global__ __launch_bounds__(256) void gemm_batch_kernel(GemmBatch gb) {
  const int t = blockIdx.x;
  int di = 0;
#pragma unroll
  for (int j = 1; j < 4; ++j) if (t >= gb.d[j].blkStart) di = j;
  const GemmDesc D = gb.d[di];
  const int rel = t - D.blkStart;
  const int tileN = (rel % D.nTX) * 128;
  const int tileM = (rel / D.nTX) * 128;

  __shared__ bf16 ldsA[128 * 32];
  __shared__ bf16 ldsB[128 * 32];
  const int tid = threadIdx.x;
  const int lane = tid & 63;
  const int w = tid >> 6;
  const int wr = w >> 1, wc = w & 1;
  const int l15 = lane & 15, lg = lane >> 4;
  const int lrow = lane >> 2;
  const int lcol = (lane & 3) * 8;

  f32x4 acc[4][4] = {};

  for (int k0 = 0; k0 < D.K; k0 += 32) {
    async_load16(D.A  + (size_t)(tileM + w * 32 +      lrow) * D.lda + k0 + lcol, &ldsA[(w * 32) * 32]);
    async_load16(D.A  + (size_t)(tileM + w * 32 + 16 + lrow) * D.lda + k0 + lcol, &ldsA[(w * 32 + 16) * 32]);
    async_load16(D.WT + (size_t)(tileN + w * 32 +      lrow) * D.ldb + k0 + lcol, &ldsB[(w * 32) * 32]);
    async_load16(D.WT + (size_t)(tileN + w * 32 + 16 + lrow) * D.ldb + k0 + lcol, &ldsB[(w * 32 + 16) * 32]);
    __syncthreads();

    bf16x8 af[4], bfr[4];
#pragma unroll
    for (int i = 0; i < 4; ++i) {
      af[i]  = *(const bf16x8*)&ldsA[(wr * 64 + i * 16 + l15) * 32 + lg * 8];
      bfr[i] = *(const bf16x8*)&ldsB[(wc * 64 + i * 16 + l15) * 32 + lg * 8];
    }
#pragma unroll
    for (int i = 0; i < 4; ++i)
#pragma unroll
      for (int j = 0; j < 4; ++j)
        acc[i][j] = __builtin_amdgcn_mfma_f32_16x16x32_bf16(af[i], bfr[j], acc[i][j], 0, 0, 0);
    __syncthreads();
  }

  const int mbase = tileM + wr * 64;
  const int nbase = tileN + wc * 64;
#pragma unroll
  for (int j = 0; j < 4; ++j) {
    int col = nbase + j * 16 + l15;
    float bvc = D.biasRow ? 0.0f : (col < D.bsplit ? D.b1[col] : D.b2[col - D.bsplit]);
    if (D.addm) {
      const int pcol = col >> 1;
      const bool odd = (col & 1) != 0;
#pragma unroll
      for (int i = 0; i < 4; ++i)
#pragma unroll
        for (int r = 0; r < 4; ++r) {
          int row = mbase + i * 16 + lg * 4 + r;
          unsigned int pr = *(const unsigned int*)((const char*)D.addm +
                              (size_t)row * D.ldc * 2 + (size_t)(col & ~1) * 2);
          float ke = bfu2f((unsigned short)(pr & 0xffff));
          float ko = bfu2f((unsigned short)(pr >> 16));
          float add;
          if (pcol == 0) {
            float rr = (float)(row & (Ss - 1)) * (1.0f / 512.0f);
            float c = cosf(rr), sn = sinf(rr);
            add = odd ? (ko * c + ke * sn) : (ke * c - ko * sn);
          } else {
            add = odd ? ko : ke;           // rope == identity for p>=1 at bf16
          }
          D.C[(size_t)row * D.ldc + col] = f2bf(acc[i][j][r] + bvc + add);
        }
    } else {
#pragma unroll
      for (int i = 0; i < 4; ++i)
#pragma unroll
        for (int r = 0; r < 4; ++r) {
          int row = mbase + i * 16 + lg * 4 + r;
          float bv = D.biasRow ? D.b1[row] : bvc;
          D.C[(size_t)row * D.ldc + col] = f2bf(acc[i][j][r] + bv);
        }
    }
  }
}

// ---------------------------------------------------------------- GEMM fp32-out (outproj), 128x64 tiles
__global__ __launch_bounds__(256) void gemm_kernel_f32(
    const bf16* __restrict__ A, int lda,
    const bf16* __restrict__ WT, int ldb,
    const float* __restrict__ b1,
    float* __restrict__ Cout, int ldc, int K) {
  __shared__ bf16 ldsA[128 * 32];
  __shared__ bf16 ldsB[64 * 32];
  const int tid = threadIdx.x;
  const int lane = tid & 63;
  const int w = tid >> 6;
  const int tileM = blockIdx.y * 128;
  const int tileN = blockIdx.x * 64;
  const int l15 = lane & 15, lg = lane >> 4;
  const int lrow = lane >> 2;
  const int lcol = (lane & 3) * 8;

  f32x4 acc[2][4] = {};

  for (int k0 = 0; k0 < K; k0 += 32) {
    async_load16(A  + (size_t)(tileM + w * 32 +      lrow) * lda + k0 + lcol, &ldsA[(w * 32) * 32]);
    async_load16(A  + (size_t)(tileM + w * 32 + 16 + lrow) * lda + k0 + lcol, &ldsA[(w * 32 + 16) * 32]);
    async_load16(WT + (size_t)(tileN + w * 16 + lrow) * ldb + k0 + lcol, &ldsB[(w * 16) * 32]);
    __syncthreads();

    bf16x8 af[2], bfr[4];
#pragma unroll
    for (int i = 0; i < 2; ++i)
      af[i]  = *(const bf16x8*)&ldsA[(w * 32 + i * 16 + l15) * 32 + lg * 8];
#pragma unroll
    for (int j = 0; j < 4; ++j)
      bfr[j] = *(const bf16x8*)&ldsB[(j * 16 + l15) * 32 + lg * 8];
#pragma unroll
    for (int i = 0; i < 2; ++i)
#pragma unroll
      for (int j = 0; j < 4; ++j)
        acc[i][j] = __builtin_amdgcn_mfma_f32_16x16x32_bf16(af[i], bfr[j], acc[i][j], 0, 0, 0);
    __syncthreads();
  }

#pragma unroll
  for (int j = 0; j < 4; ++j) {
    int col = tileN + j * 16 + l15;
    float bvc = b1[col];
#pragma unroll
    for (int i = 0; i < 2; ++i)
#pragma unroll
      for (int r = 0; r < 4; ++r) {
        int row = tileM + w * 32 + i * 16 + lg * 4 + r;
        Cout[(size_t)row * ldc + col] = acc[i][j][r] + bvc;
      }
  }
}

// ---------------------------------------------------------------- Q p=0 fixup
__global__ __launch_bounds__(256) void fixup_q_kernel(
    const bf16* __restrict__ ct, const float* __restrict__ Wqr,
    const float* __restrict__ Wqr_b, bf16* __restrict__ Q) {
  const int row = blockIdx.x * 4 + (threadIdx.x >> 6);
  const int lane = threadIdx.x & 63;
  const bf16* cr = ct + (size_t)row * 1024 + lane * 8;      // ct_q = cols [0,512)
  const float* wq = Wqr + (size_t)(lane * 8) * 1024;
  float q0 = 0.f, q1 = 0.f;
#pragma unroll
  for (int e = 0; e < 8; ++e) {
    float xv = bf2f(cr[e]);
    q0 = fmaf(xv, wq[e * 1024 + 0], q0);
    q1 = fmaf(xv, wq[e * 1024 + 1], q1);
  }
#pragma unroll
  for (int d = 32; d >= 1; d >>= 1) {
    q0 += __shfl_xor(q0, d, 64);
    q1 += __shfl_xor(q1, d, 64);
  }
  if (lane == 0) {
    const float Qr0 = q0 + Wqr_b[0], Qr1 = q1 + Wqr_b[1];
    const float rr = (float)(row & (Ss - 1)) * (1.0f / 512.0f);
    const float cm1 = cosf(rr) - 1.0f, sn = sinf(rr);
    const size_t base = (size_t)row * DMODEL;
    Q[base]     = f2bf(bf2f(Q[base])     + Qr0 * cm1 - Qr1 * sn);
    Q[base + 1] = f2bf(bf2f(Q[base + 1]) + Qr1 * cm1 + Qr0 * sn);
  }
}

// ---------------------------------------------------------------- attention v8 (split-KV x2)
// grid (32 bh, 32); y -> qt = y>>1, sk = y&1. Each block: 16 kv-tiles (1024 keys).
// Writes UNNORMALIZED O partial (bf16) + per-row (m, l) for the combine pass.
__global__ __launch_bounds__(256) void attn_kernel(
    const bf16* __restrict__ Qm, const bf16* __restrict__ Kn,
    const bf16* __restrict__ VT, bf16* __restrict__ Op0, bf16* __restrict__ Op1,
    float2* __restrict__ mlbuf) {
  const int bh = blockIdx.x;                    // bh%8 == XCD -> K/V stays in one L2
  const int qt = blockIdx.y >> 1, sk = blockIdx.y & 1;
  const int b = bh >> 4, h = bh & 15;
  const int tid = threadIdx.x, lane = tid & 63, w = tid >> 6;
  const int q0 = qt * 128 + w * 32;
  const int l15 = lane & 15, lg = lane >> 4;
  const float SC2 = 0.044736075f;    // (1/sqrt(1040)) * log2(e)
  const float THR = 11.5415603f;     // 8 * log2(e)

  __shared__ bf16 ldsK[2][64 * 64];
  __shared__ bf16 ldsV[2][64 * 64];
  __shared__ bf16 ldsP[4][32 * 64];

  bf16* __restrict__ Opart = sk ? Op1 : Op0;
  const bf16* Kg = Kn + (size_t)(b * Ss) * DMODEL + h * 64;
  const bf16* Vg = VT + (size_t)(h * 64) * NTOK + b * Ss;

  const int r0 = tid >> 3;
  const int srcb = ((tid & 7) * 16) ^ ((r0 & 7) << 4);
  const int kvbase = sk * 1024;                 // this split's first key
  const char* kS0 = (const char*)(Kg + (size_t)(kvbase + r0) * DMODEL) + srcb;
  const char* kS1 = (const char*)(Kg + (size_t)(kvbase + 32 + r0) * DMODEL) + srcb;
  const char* vS0 = (const char*)(Vg + (size_t)r0 * NTOK + kvbase) + srcb;
  const char* vS1 = (const char*)(Vg + (size_t)(32 + r0) * NTOK + kvbase) + srcb;
  const ptrdiff_t kAdv = (ptrdiff_t)64 * DMODEL * 2;
  const ptrdiff_t vAdv = 128;

  bf16* kd0_b0 = &ldsK[0][w * 512]; bf16* kd1_b0 = &ldsK[0][2048 + w * 512];
  bf16* kd0_b1 = &ldsK[1][w * 512]; bf16* kd1_b1 = &ldsK[1][2048 + w * 512];
  bf16* vd0_b0 = &ldsV[0][w * 512]; bf16* vd1_b0 = &ldsV[0][2048 + w * 512];
  bf16* vd0_b1 = &ldsV[1][w * 512]; bf16* vd1_b1 = &ldsV[1][2048 + w * 512];

  auto stageTo = [&](bf16* kd0, bf16* kd1, bf16* vd0, bf16* vd1) {
    async_load16((const bf16*)kS0, kd0);
    async_load16((const bf16*)kS1, kd1);
    async_load16((const bf16*)vS0, vd0);
    async_load16((const bf16*)vS1, vd1);
    kS0 += kAdv; kS1 += kAdv; vS0 += vAdv; vS1 += vAdv;
  };

  stageTo(kd0_b0, kd1_b0, vd0_b0, vd1_b0);   // tile 0 in flight while Q loads

  const int kswz = (l15 & 7) << 4;
  const int xA = (lg * 16) ^ kswz;
  const int xB = (64 + lg * 16) ^ kswz;
  const char* krA0 = (const char*)&ldsK[0][0] + l15 * 128 + xA;
  const char* krB0 = (const char*)&ldsK[0][0] + l15 * 128 + xB;
  const char* krA1 = (const char*)&ldsK[1][0] + l15 * 128 + xA;
  const char* krB1 = (const char*)&ldsK[1][0] + l15 * 128 + xB;
  const char* vrA0 = (const char*)&ldsV[0][0] + l15 * 128 + xA;
  const char* vrB0 = (const char*)&ldsV[0][0] + l15 * 128 + xB;
  const char* vrA1 = (const char*)&ldsV[1][0] + l15 * 128 + xA;
  const char* vrB1 = (const char*)&ldsV[1][0] + l15 * 128 + xB;

  char* Pw = (char*)&ldsP[w][0];
  char* pwr[4];
#pragma unroll
  for (int j = 0; j < 4; ++j) {
    const int chunk = (j * 2 + (lg >> 1)) ^ (l15 & 7);
    pwr[j] = Pw + l15 * 128 + chunk * 16 + (lg & 1) * 8;
  }
  const char* paA = Pw + l15 * 128 + xA;
  const char* paB = Pw + l15 * 128 + xB;

  bf16x8 bq[2][2];
#pragma unroll
  for (int i = 0; i < 2; ++i) {
    const size_t rowoff = (size_t)(b * Ss + q0 + i * 16 + l15) * DMODEL + h * 64;
    bq[i][0] = *(const bf16x8*)&Qm[rowoff + lg * 8];
    bq[i][1] = *(const bf16x8*)&Qm[rowoff + 32 + lg * 8];
  }

  float m[2] = { 0.0f, 0.0f }, l[2] = { 0.0f, 0.0f };   // l = per-lane partial
  f32x4 accO[2][4] = {};

  auto body = [&](const char* krA, const char* krB, const char* vrA, const char* vrB) {
    f32x4 sa[4][2] = {};
    __builtin_amdgcn_s_setprio(1);
#pragma unroll
    for (int j = 0; j < 4; ++j) {
      bf16x8 ak0 = *(const bf16x8*)(krA + j * 2048);
      bf16x8 ak1 = *(const bf16x8*)(krB + j * 2048);
#pragma unroll
      for (int i = 0; i < 2; ++i) {
        sa[j][i] = __builtin_amdgcn_mfma_f32_16x16x32_bf16(ak0, bq[i][0], sa[j][i], 0, 0, 0);
        sa[j][i] = __builtin_amdgcn_mfma_f32_16x16x32_bf16(ak1, bq[i][1], sa[j][i], 0, 0, 0);
      }
    }
    __builtin_amdgcn_s_setprio(0);
#pragma unroll
    for (int i = 0; i < 2; ++i) {
      float pmaxr = -3.0e38f;
#pragma unroll
      for (int j = 0; j < 4; ++j)
#pragma unroll
        for (int r = 0; r < 4; ++r) pmaxr = fmaxf(pmaxr, sa[j][i][r]);
      if (__any(fmaf(pmaxr, SC2, -m[i]) > THR)) {        // cold on sane logits
        float px = fmaxf(pmaxr, __shfl_xor(pmaxr, 16, 64));
        px = fmaxf(px, __shfl_xor(px, 32, 64));
        float mnew = fmaxf(m[i], px * SC2);
        float corr = __builtin_amdgcn_exp2f(m[i] - mnew);
        m[i] = mnew; l[i] *= corr;
        float cr[4];
#pragma unroll
        for (int r = 0; r < 4; ++r) cr[r] = __shfl(corr, lg * 4 + r, 64);
#pragma unroll
        for (int dj = 0; dj < 4; ++dj)
#pragma unroll
          for (int r = 0; r < 4; ++r) accO[i][dj][r] *= cr[r];
      }
      float p[4][4];
      float ts = 0.f;
#pragma unroll
      for (int j = 0; j < 4; ++j)
#pragma unroll
        for (int r = 0; r < 4; ++r) {
          p[j][r] = __builtin_amdgcn_exp2f(fmaf(sa[j][i][r], SC2, -m[i]));
          ts += p[j][r];
        }
      l[i] += ts;                                        // per-lane partial
#pragma unroll
      for (int j = 0; j < 4; ++j) {
        uint2 pw;
        pw.x = packbf(p[j][0], p[j][1]);
        pw.y = packbf(p[j][2], p[j][3]);
        *(uint2*)(pwr[j] + i * 2048) = pw;
      }
    }
    bf16x8 pa[2][2];
#pragma unroll
    for (int i = 0; i < 2; ++i) {
      pa[i][0] = *(const bf16x8*)(paA + i * 2048);
      pa[i][1] = *(const bf16x8*)(paB + i * 2048);
    }
    __builtin_amdgcn_s_setprio(1);
#pragma unroll
    for (int dj = 0; dj < 4; ++dj) {
      bf16x8 bv0 = *(const bf16x8*)(vrA + dj * 2048);
      bf16x8 bv1 = *(const bf16x8*)(vrB + dj * 2048);
#pragma unroll
      for (int i = 0; i < 2; ++i) {
        accO[i][dj] = __builtin_amdgcn_mfma_f32_16x16x32_bf16(pa[i][0], bv0, accO[i][dj], 0, 0, 0);
        accO[i][dj] = __builtin_amdgcn_mfma_f32_16x16x32_bf16(pa[i][1], bv1, accO[i][dj], 0, 0, 0);
      }
    }
    __builtin_amdgcn_s_setprio(0);
  };

  for (int tt = 0; tt < 8; ++tt) {                   // 16 tiles = this split's 1024 keys
    __syncthreads();                                 // buf0 ready; buf1 free
    stageTo(kd0_b1, kd1_b1, vd0_b1, vd1_b1);
    body(krA0, krB0, vrA0, vrB0);
    __syncthreads();                                 // buf1 ready; buf0 free
    if (tt < 7) stageTo(kd0_b0, kd1_b0, vd0_b0, vd1_b0);
    body(krA1, krB1, vrA1, vrB1);
  }

  // ---- epilogue: write UNNORMALIZED O partial + (m, l) per q-row
#pragma unroll
  for (int i = 0; i < 2; ++i) {
    float lt = l[i];
    lt += __shfl_xor(lt, 16, 64);
    lt += __shfl_xor(lt, 32, 64);
    if (lg == 0)
      mlbuf[((size_t)sk * 32 + bh) * Ss + q0 + i * 16 + l15] = make_float2(m[i], lt);
#pragma unroll
    for (int dj = 0; dj < 4; ++dj)
#pragma unroll
      for (int r = 0; r < 4; ++r)
        Opart[(size_t)(b * Ss + q0 + i * 16 + lg * 4 + r) * DMODEL + h * 64 + dj * 16 + l15] =
            f2bf(accO[i][dj][r]);
  }
}

// ---------------------------------------------------------------- split-KV combine
// AO = (O0*2^(m0-M) + O1*2^(m1-M)) / (l0*2^(m0-M) + l1*2^(m1-M)); 8 cols/thread
__global__ __launch_bounds__(256) void combine_kernel(
    const bf16* __restrict__ Op0, const bf16* __restrict__ Op1,
    const float2* __restrict__ mlbuf, bf16* __restrict__ AO) {
  const int t = blockIdx.x * blockDim.x + threadIdx.x;   // NTOK*128
  const int row = t >> 7;
  const int cg = t & 127;
  const int h = cg >> 3;
  const int b = row >> 11, q = row & (Ss - 1);
  const size_t mlidx = ((size_t)(b * 16 + h)) * Ss + q;
  const float2 ml0 = mlbuf[mlidx];
  const float2 ml1 = mlbuf[(size_t)32 * Ss + mlidx];
  const float M = fmaxf(ml0.x, ml1.x);
  const float c0 = exp2f(ml0.x - M), c1 = exp2f(ml1.x - M);
  const float linv = 1.0f / (ml0.y * c0 + ml1.y * c1);
  const size_t off = (size_t)row * DMODEL + cg * 8;
  union { bf16x8 v; unsigned short u[8]; } o0, o1;
  o0.v = *(const bf16x8*)&Op0[off];
  o1.v = *(const bf16x8*)&Op1[off];
  uint4 o;
  unsigned int* op = &o.x;
#pragma unroll
  for (int j = 0; j < 4; ++j) {
    float a0 = (bfu2f(o0.u[2 * j])     * c0 + bfu2f(o1.u[2 * j])     * c1) * linv;
    float a1 = (bfu2f(o0.u[2 * j + 1]) * c0 + bfu2f(o1.u[2 * j + 1]) * c1) * linv;
    op[j] = packbf(a0, a1);
  }
  *(uint4*)&AO[off] = o;
}

// ---------------------------------------------------------------- launch
extern "C" void kernel_launch(void* const* d_in, const int* in_sizes, int n_in,
                              void* d_out, int out_size, void* d_ws, size_t ws_size,
                              hipStream_t stream) {
  const float* x      = (const float*)d_in[0];
  const float* Wdq    = (const float*)d_in[1];  const float* Wdq_b  = (const float*)d_in[2];
  const float* Wuq    = (const float*)d_in[3];  const float* Wuq_b  = (const float*)d_in[4];
  const float* Wqr    = (const float*)d_in[5];  const float* Wqr_b  = (const float*)d_in[6];
  const float* Wkr    = (const float*)d_in[7];  const float* Wkr_b  = (const float*)d_in[8];
  const float* Wdkv   = (const float*)d_in[9];  const float* Wdkv_b = (const float*)d_in[10];
  const float* Wuk    = (const float*)d_in[11]; const float* Wuk_b  = (const float*)d_in[12];
  const float* Wuv    = (const float*)d_in[13]; const float* Wuv_b  = (const float*)d_in[14];
  const float* Wo     = (const float*)d_in[15]; const float* Wo_b   = (const float*)d_in[16];

  // ---- workspace ----
  char* ws = (char*)d_ws;
  size_t off = 0;
  bf16* WdqT   = (bf16*)(ws + off); off += (size_t)512  * 1024 * 2;
  bf16* WdkvT  = (bf16*)(ws + off); off += (size_t)512  * 1024 * 2;
  bf16* WuqqrT = (bf16*)(ws + off); off += (size_t)1024 * 512  * 2;   // (Wuq+Wqr)^T
  bf16* WukT   = (bf16*)(ws + off); off += (size_t)1024 * 512  * 2;
  bf16* WuvT   = (bf16*)(ws + off); off += (size_t)1024 * 512  * 2;
  bf16* WkrT   = (bf16*)(ws + off); off += (size_t)1024 * 1024 * 2;
  bf16* WoT    = (bf16*)(ws + off); off += (size_t)1024 * 1024 * 2;
  bf16* x_bf   = (bf16*)(ws + off); off += (size_t)NTOK * 1024 * 2;   // dead after batch A -> Opart0
  bf16* ct     = (bf16*)(ws + off); off += (size_t)NTOK * 1024 * 2;   // dead after fixup  -> Opart1
  bf16* Ga     = (bf16*)(ws + off); off += (size_t)NTOK * 1024 * 2;   // Qsum, later AO
  bf16* VTr    = (bf16*)(ws + off); off += (size_t)NTOK * 1024 * 2;
  float* qsum_b= (float*)(ws + off); off += 1024 * 4;
  float2* mlb  = (float2*)(ws + off); off += (size_t)2 * 32 * Ss * 8; // 1 MB
  bf16* Kn     = (bf16*)d_out + (size_t)NTOK * DMODEL; // Kr, then final K (in-place add)
  bf16* Opart0 = x_bf;                                 // alias: dead after batch A
  bf16* Opart1 = ct;                                   // alias: dead after fixup_q
  bf16* AO     = Ga;                                   // alias: Qsum consumed by attn prologue
  (void)ws_size; (void)in_sizes; (void)n_in; (void)out_size;

  // ---- merged transpose(+add) + x convert + qsum_b ----
  TransPack tp = {{
    { Wdq,  0,   WdqT,   1024, 512,  0    },
    { Wdkv, 0,   WdkvT,  1024, 512,  128  },
    { Wuq,  Wqr, WuqqrT, 512,  1024, 256  },
    { Wuk,  0,   WukT,   512,  1024, 384  },
    { Wuv,  0,   WuvT,   512,  1024, 512  },
    { Wkr,  0,   WkrT,   1024, 1024, 640  },
    { Wo,   0,   WoT,    1024, 1024, 896  },
    { 0, 0, 0, 0, 0, 1 << 30 },
  }};
  trans_conv_kernel<<<1152 + 4096 + 4, 256, 0, stream>>>(
      tp, x, x_bf, 1152, Wuq_b, Wqr_b, qsum_b, 1152 + 4096);

  // ---- batch A (512): down = x@[Wdq|Wdkv] -> ct ; Kr = x@Wkr + kr_b -> Kn ----
  GemmBatch ba = {{
    { x_bf, WdqT, Wdq_b, Wdkv_b, 0, ct, 1024, 1024, 1024, 1024, 512,     8, 0,       0 },
    { x_bf, WkrT, Wkr_b, Wkr_b,  0, Kn, 1024, 1024, 1024, 1024, INT_MAX, 8, 256,     0 },
    { 0, 0, 0, 0, 0, 0, 0, 0, 0, 0, 0, 1, INT_MAX, 0 },
    { 0, 0, 0, 0, 0, 0, 0, 0, 0, 0, 0, 1, INT_MAX, 0 },
  }};
  gemm_batch_kernel<<<512, 256, 0, stream>>>(ba);

  // ---- batch B (768): Qsum -> Ga ; K = upK + Kr(identity-rope, trig pair 0) in place ; V^T ----
  GemmBatch bb = {{
    { ct,       WuqqrT,   qsum_b, qsum_b, 0,  Ga,  1024, 512,  1024, 512, INT_MAX, 8,  0,   0 },
    { ct + 512, WukT,     Wuk_b,  Wuk_b,  Kn, Kn,  1024, 512,  1024, 512, INT_MAX, 8,  256, 0 },
    { WuvT,     ct + 512, Wuv_b,  Wuv_b,  0,  VTr, 512,  1024, NTOK, 512, INT_MAX, 32, 512, 1 },
    { 0, 0, 0, 0, 0, 0, 0, 0, 0, 0, 0, 1, 1 << 30, 0 },
  }};
  gemm_batch_kernel<<<768, 256, 0, stream>>>(bb);

  // ---- Q p=0 fixup (dims 0,1 of Qsum) ----
  fixup_q_kernel<<<NTOK / 4, 256, 0, stream>>>(ct, Wqr, Wqr_b, Ga);

  // ---- attention, split-KV x2 (1024 blocks = 4/CU) ----
  attn_kernel<<<dim3(32, 32), 256, 0, stream>>>(Ga, Kn, VTr, Opart0, Opart1, mlb);

  // ---- combine partials -> AO ----
  combine_kernel<<<NTOK * 128 / 256, 256, 0, stream>>>(Opart0, Opart1, mlb, AO);

  // ---- output projection ----
  gemm_kernel_f32<<<dim3(16, 32), 256, 0, stream>>>(
      AO, 1024, WoT, 1024, Wo_b, (float*)d_out, 1024, 1024);
}

// Round 15
// 164.474 us; speedup vs baseline: 1.0727x; 1.0727x over previous
//
#include <hip/hip_runtime.h>
#include <hip/hip_bf16.h>
#include <math.h>
#include <limits.h>

typedef __hip_bfloat16 bf16;
typedef __bf16 bf16x8 __attribute__((ext_vector_type(8)));
typedef float  f32x4  __attribute__((ext_vector_type(4)));

#define DEVI __device__ __forceinline__

static constexpr int Bb     = 2;
static constexpr int Ss     = 2048;
static constexpr int DMODEL = 1024;
static constexpr int NTOK   = Bb * Ss;   // 4096

DEVI float bf2f(bf16 v) { return __bfloat162float(v); }
DEVI bf16  f2bf(float v) { return __float2bfloat16(v); }

DEVI unsigned int packbf(float lo, float hi) {
  union { bf16 b; unsigned short u; } a, c;
  a.b = f2bf(lo); c.b = f2bf(hi);
  return ((unsigned int)c.u << 16) | a.u;
}
DEVI float bfu2f(unsigned short u) {
  unsigned int x = (unsigned int)u << 16;
  float f; __builtin_memcpy(&f, &x, 4); return f;
}

DEVI void async_load16(const bf16* g, bf16* l) {
  __builtin_amdgcn_global_load_lds((const __attribute__((address_space(1))) void*)g,
                                   (__attribute__((address_space(3))) void*)l, 16, 0, 0);
}

// ---------------------------------------------------------------- transpose(+add) + convert + bias-sum
struct TransDesc { const float* src; const float* src2; bf16* dst; int R; int C; int tstart; };
struct TransPack { TransDesc d[8]; };

__global__ __launch_bounds__(256) void trans_conv_kernel(
    TransPack p, const float* __restrict__ cx, bf16* __restrict__ cxo, int tstartConv,
    const float* __restrict__ ba1, const float* __restrict__ ba2,
    float* __restrict__ bsum, int tstartB) {
  __shared__ bf16 tl[64][65];
  const int t = blockIdx.x;
  if (t >= tstartB) {
    const int j = (t - tstartB) * 256 + threadIdx.x;
    bsum[j] = ba1[j] + ba2[j];
    return;
  }
  if (t >= tstartConv) {
    const int idx = (t - tstartConv) * 256 + threadIdx.x;
    const float4 v = ((const float4*)cx)[idx];
    uint2 o; o.x = packbf(v.x, v.y); o.y = packbf(v.z, v.w);
    *(uint2*)&cxo[(size_t)idx * 4] = o;
    return;
  }
  int i = 0;
#pragma unroll
  for (int j = 1; j < 8; ++j) if (t >= p.d[j].tstart) i = j;
  const float* __restrict__ in  = p.d[i].src;
  const float* __restrict__ in2 = p.d[i].src2;
  bf16* __restrict__ out = p.d[i].dst;
  const int R = p.d[i].R, C = p.d[i].C;
  const int rel = t - p.d[i].tstart;
  const int tilesC = C >> 6;
  const int r0 = (rel / tilesC) * 64, c0 = (rel % tilesC) * 64;
  const int tc = threadIdx.x & 63, tr = threadIdx.x >> 6;
#pragma unroll
  for (int q = 0; q < 16; ++q) {
    int r = tr + q * 4;
    float v = in[(size_t)(r0 + r) * C + c0 + tc];
    if (in2) v += in2[(size_t)(r0 + r) * C + c0 + tc];
    tl[r][tc] = f2bf(v);
  }
  __syncthreads();
#pragma unroll
  for (int q = 0; q < 16; ++q) {
    int r = tr + q * 4;
    out[(size_t)(c0 + r) * R + r0 + tc] = tl[tc][r];
  }
}

// ---------------------------------------------------------------- batched GEMM (+optional in-place Kr-add)
// XCD-swizzled block order within each desc: rel' = (rel%8)*(nBlk/8) + rel/8
struct GemmDesc {
  const bf16* A; const bf16* WT; const float* b1; const float* b2; const bf16* addm; bf16* C;
  int lda, ldb, ldc, K, bsplit, nTX, blkStart, nBlk, biasRow;
};
struct GemmBatch { GemmDesc d[4]; };

__global__ __launch_bounds__(256) void gemm_batch_kernel(GemmBatch gb) {
  const int t = blockIdx.x;
  int di = 0;
#pragma unroll
  for (int j = 1; j < 4; ++j) if (t >= gb.d[j].blkStart) di = j;
  const GemmDesc D = gb.d[di];
  int rel = t - D.blkStart;
  if ((D.nBlk & 7) == 0) rel = (rel & 7) * (D.nBlk >> 3) + (rel >> 3);  // XCD chunk-swizzle
  const int tileN = (rel % D.nTX) * 128;
  const int tileM = (rel / D.nTX) * 128;

  __shared__ bf16 ldsA[128 * 32];
  __shared__ bf16 ldsB[128 * 32];
  const int tid = threadIdx.x;
  const int lane = tid & 63;
  const int w = tid >> 6;
  const int wr = w >> 1, wc = w & 1;
  const int l15 = lane & 15, lg = lane >> 4;
  const int lrow = lane >> 2;
  const int lcol = (lane & 3) * 8;

  f32x4 acc[4][4] = {};

  for (int k0 = 0; k0 < D.K; k0 += 32) {
    async_load16(D.A  + (size_t)(tileM + w * 32 +      lrow) * D.lda + k0 + lcol, &ldsA[(w * 32) * 32]);
    async_load16(D.A  + (size_t)(tileM + w * 32 + 16 + lrow) * D.lda + k0 + lcol, &ldsA[(w * 32 + 16) * 32]);
    async_load16(D.WT + (size_t)(tileN + w * 32 +      lrow) * D.ldb + k0 + lcol, &ldsB[(w * 32) * 32]);
    async_load16(D.WT + (size_t)(tileN + w * 32 + 16 + lrow) * D.ldb + k0 + lcol, &ldsB[(w * 32 + 16) * 32]);
    __syncthreads();

    bf16x8 af[4], bfr[4];
#pragma unroll
    for (int i = 0; i < 4; ++i) {
      af[i]  = *(const bf16x8*)&ldsA[(wr * 64 + i * 16 + l15) * 32 + lg * 8];
      bfr[i] = *(const bf16x8*)&ldsB[(wc * 64 + i * 16 + l15) * 32 + lg * 8];
    }
#pragma unroll
    for (int i = 0; i < 4; ++i)
#pragma unroll
      for (int j = 0; j < 4; ++j)
        acc[i][j] = __builtin_amdgcn_mfma_f32_16x16x32_bf16(af[i], bfr[j], acc[i][j], 0, 0, 0);
    __syncthreads();
  }

  const int mbase = tileM + wr * 64;
  const int nbase = tileN + wc * 64;
#pragma unroll
  for (int j = 0; j < 4; ++j) {
    int col = nbase + j * 16 + l15;
    float bvc = D.biasRow ? 0.0f : (col < D.bsplit ? D.b1[col] : D.b2[col - D.bsplit]);
    if (D.addm) {
      const int pcol = col >> 1;
      const bool odd = (col & 1) != 0;
#pragma unroll
      for (int i = 0; i < 4; ++i)
#pragma unroll
        for (int r = 0; r < 4; ++r) {
          int row = mbase + i * 16 + lg * 4 + r;
          unsigned int pr = *(const unsigned int*)((const char*)D.addm +
                              (size_t)row * D.ldc * 2 + (size_t)(col & ~1) * 2);
          float ke = bfu2f((unsigned short)(pr & 0xffff));
          float ko = bfu2f((unsigned short)(pr >> 16));
          float add;
          if (pcol == 0) {
            float rr = (float)(row & (Ss - 1)) * (1.0f / 512.0f);
            float c = cosf(rr), sn = sinf(rr);
            add = odd ? (ko * c + ke * sn) : (ke * c - ko * sn);
          } else {
            add = odd ? ko : ke;           // rope == identity for p>=1 at bf16
          }
          D.C[(size_t)row * D.ldc + col] = f2bf(acc[i][j][r] + bvc + add);
        }
    } else {
#pragma unroll
      for (int i = 0; i < 4; ++i)
#pragma unroll
        for (int r = 0; r < 4; ++r) {
          int row = mbase + i * 16 + lg * 4 + r;
          float bv = D.biasRow ? D.b1[row] : bvc;
          D.C[(size_t)row * D.ldc + col] = f2bf(acc[i][j][r] + bv);
        }
    }
  }
}

// ---------------------------------------------------------------- GEMM fp32-out (outproj), 128x64 tiles, XCD-swizzled
__global__ __launch_bounds__(256) void gemm_kernel_f32(
    const bf16* __restrict__ A, int lda,
    const bf16* __restrict__ WT, int ldb,
    const float* __restrict__ b1,
    float* __restrict__ Cout, int ldc, int K) {
  __shared__ bf16 ldsA[128 * 32];
  __shared__ bf16 ldsB[64 * 32];
  const int nBlk = gridDim.x * gridDim.y;
  int id = blockIdx.y * gridDim.x + blockIdx.x;
  id = (id & 7) * (nBlk >> 3) + (id >> 3);             // XCD chunk-swizzle
  const int tileM = (id / gridDim.x) * 128;
  const int tileN = (id % gridDim.x) * 64;
  const int tid = threadIdx.x;
  const int lane = tid & 63;
  const int w = tid >> 6;
  const int l15 = lane & 15, lg = lane >> 4;
  const int lrow = lane >> 2;
  const int lcol = (lane & 3) * 8;

  f32x4 acc[2][4] = {};

  for (int k0 = 0; k0 < K; k0 += 32) {
    async_load16(A  + (size_t)(tileM + w * 32 +      lrow) * lda + k0 + lcol, &ldsA[(w * 32) * 32]);
    async_load16(A  + (size_t)(tileM + w * 32 + 16 + lrow) * lda + k0 + lcol, &ldsA[(w * 32 + 16) * 32]);
    async_load16(WT + (size_t)(tileN + w * 16 + lrow) * ldb + k0 + lcol, &ldsB[(w * 16) * 32]);
    __syncthreads();

    bf16x8 af[2], bfr[4];
#pragma unroll
    for (int i = 0; i < 2; ++i)
      af[i]  = *(const bf16x8*)&ldsA[(w * 32 + i * 16 + l15) * 32 + lg * 8];
#pragma unroll
    for (int j = 0; j < 4; ++j)
      bfr[j] = *(const bf16x8*)&ldsB[(j * 16 + l15) * 32 + lg * 8];
#pragma unroll
    for (int i = 0; i < 2; ++i)
#pragma unroll
      for (int j = 0; j < 4; ++j)
        acc[i][j] = __builtin_amdgcn_mfma_f32_16x16x32_bf16(af[i], bfr[j], acc[i][j], 0, 0, 0);
    __syncthreads();
  }

#pragma unroll
  for (int j = 0; j < 4; ++j) {
    int col = tileN + j * 16 + l15;
    float bvc = b1[col];
#pragma unroll
    for (int i = 0; i < 2; ++i)
#pragma unroll
      for (int r = 0; r < 4; ++r) {
        int row = tileM + w * 32 + i * 16 + lg * 4 + r;
        Cout[(size_t)row * ldc + col] = acc[i][j][r] + bvc;
      }
  }
}

// ---------------------------------------------------------------- Q p=0 fixup
__global__ __launch_bounds__(256) void fixup_q_kernel(
    const bf16* __restrict__ ct, const float* __restrict__ Wqr,
    const float* __restrict__ Wqr_b, bf16* __restrict__ Q) {
  const int row = blockIdx.x * 4 + (threadIdx.x >> 6);
  const int lane = threadIdx.x & 63;
  const bf16* cr = ct + (size_t)row * 1024 + lane * 8;      // ct_q = cols [0,512)
  const float* wq = Wqr + (size_t)(lane * 8) * 1024;
  float q0 = 0.f, q1 = 0.f;
#pragma unroll
  for (int e = 0; e < 8; ++e) {
    float xv = bf2f(cr[e]);
    q0 = fmaf(xv, wq[e * 1024 + 0], q0);
    q1 = fmaf(xv, wq[e * 1024 + 1], q1);
  }
#pragma unroll
  for (int d = 32; d >= 1; d >>= 1) {
    q0 += __shfl_xor(q0, d, 64);
    q1 += __shfl_xor(q1, d, 64);
  }
  if (lane == 0) {
    const float Qr0 = q0 + Wqr_b[0], Qr1 = q1 + Wqr_b[1];
    const float rr = (float)(row & (Ss - 1)) * (1.0f / 512.0f);
    const float cm1 = cosf(rr) - 1.0f, sn = sinf(rr);
    const size_t base = (size_t)row * DMODEL;
    Q[base]     = f2bf(bf2f(Q[base])     + Qr0 * cm1 - Qr1 * sn);
    Q[base + 1] = f2bf(bf2f(Q[base + 1]) + Qr1 * cm1 + Qr0 * sn);
  }
}

// ---------------------------------------------------------------- attention v7 (round-13, reverted from split-KV)
__global__ __launch_bounds__(256) void attn_kernel(
    const bf16* __restrict__ Qm, const bf16* __restrict__ Kn,
    const bf16* __restrict__ VT, bf16* __restrict__ AO) {
  const int bh = blockIdx.x, qt = blockIdx.y;   // bh%8 == XCD -> K/V stays in one L2
  const int b = bh >> 4, h = bh & 15;
  const int tid = threadIdx.x, lane = tid & 63, w = tid >> 6;
  const int q0 = qt * 128 + w * 32;
  const int l15 = lane & 15, lg = lane >> 4;
  const float SC2 = 0.044736075f;    // (1/sqrt(1040)) * log2(e)
  const float THR = 11.5415603f;     // 8 * log2(e)

  __shared__ bf16 ldsK[2][64 * 64];
  __shared__ bf16 ldsV[2][64 * 64];
  __shared__ bf16 ldsP[4][32 * 64];

  const bf16* Kg = Kn + (size_t)(b * Ss) * DMODEL + h * 64;
  const bf16* Vg = VT + (size_t)(h * 64) * NTOK + b * Ss;

  const int r0 = tid >> 3;
  const int srcb = ((tid & 7) * 16) ^ ((r0 & 7) << 4);
  const char* kS0 = (const char*)(Kg + (size_t)r0 * DMODEL) + srcb;
  const char* kS1 = (const char*)(Kg + (size_t)(32 + r0) * DMODEL) + srcb;
  const char* vS0 = (const char*)(Vg + (size_t)r0 * NTOK) + srcb;
  const char* vS1 = (const char*)(Vg + (size_t)(32 + r0) * NTOK) + srcb;
  const ptrdiff_t kAdv = (ptrdiff_t)64 * DMODEL * 2;
  const ptrdiff_t vAdv = 128;

  bf16* kd0_b0 = &ldsK[0][w * 512]; bf16* kd1_b0 = &ldsK[0][2048 + w * 512];
  bf16* kd0_b1 = &ldsK[1][w * 512]; bf16* kd1_b1 = &ldsK[1][2048 + w * 512];
  bf16* vd0_b0 = &ldsV[0][w * 512]; bf16* vd1_b0 = &ldsV[0][2048 + w * 512];
  bf16* vd0_b1 = &ldsV[1][w * 512]; bf16* vd1_b1 = &ldsV[1][2048 + w * 512];

  auto stageTo = [&](bf16* kd0, bf16* kd1, bf16* vd0, bf16* vd1) {
    async_load16((const bf16*)kS0, kd0);
    async_load16((const bf16*)kS1, kd1);
    async_load16((const bf16*)vS0, vd0);
    async_load16((const bf16*)vS1, vd1);
    kS0 += kAdv; kS1 += kAdv; vS0 += vAdv; vS1 += vAdv;
  };

  stageTo(kd0_b0, kd1_b0, vd0_b0, vd1_b0);   // tile 0 in flight while Q loads

  const int kswz = (l15 & 7) << 4;
  const int xA = (lg * 16) ^ kswz;
  const int xB = (64 + lg * 16) ^ kswz;
  const char* krA0 = (const char*)&ldsK[0][0] + l15 * 128 + xA;
  const char* krB0 = (const char*)&ldsK[0][0] + l15 * 128 + xB;
  const char* krA1 = (const char*)&ldsK[1][0] + l15 * 128 + xA;
  const char* krB1 = (const char*)&ldsK[1][0] + l15 * 128 + xB;
  const char* vrA0 = (const char*)&ldsV[0][0] + l15 * 128 + xA;
  const char* vrB0 = (const char*)&ldsV[0][0] + l15 * 128 + xB;
  const char* vrA1 = (const char*)&ldsV[1][0] + l15 * 128 + xA;
  const char* vrB1 = (const char*)&ldsV[1][0] + l15 * 128 + xB;

  char* Pw = (char*)&ldsP[w][0];
  char* pwr[4];
#pragma unroll
  for (int j = 0; j < 4; ++j) {
    const int chunk = (j * 2 + (lg >> 1)) ^ (l15 & 7);
    pwr[j] = Pw + l15 * 128 + chunk * 16 + (lg & 1) * 8;
  }
  const char* paA = Pw + l15 * 128 + xA;
  const char* paB = Pw + l15 * 128 + xB;

  bf16x8 bq[2][2];
#pragma unroll
  for (int i = 0; i < 2; ++i) {
    const size_t rowoff = (size_t)(b * Ss + q0 + i * 16 + l15) * DMODEL + h * 64;
    bq[i][0] = *(const bf16x8*)&Qm[rowoff + lg * 8];
    bq[i][1] = *(const bf16x8*)&Qm[rowoff + 32 + lg * 8];
  }

  float m[2] = { 0.0f, 0.0f }, l[2] = { 0.0f, 0.0f };   // l = per-lane partial
  f32x4 accO[2][4] = {};

  auto body = [&](const char* krA, const char* krB, const char* vrA, const char* vrB) {
    f32x4 sa[4][2] = {};
    __builtin_amdgcn_s_setprio(1);
#pragma unroll
    for (int j = 0; j < 4; ++j) {
      bf16x8 ak0 = *(const bf16x8*)(krA + j * 2048);
      bf16x8 ak1 = *(const bf16x8*)(krB + j * 2048);
#pragma unroll
      for (int i = 0; i < 2; ++i) {
        sa[j][i] = __builtin_amdgcn_mfma_f32_16x16x32_bf16(ak0, bq[i][0], sa[j][i], 0, 0, 0);
        sa[j][i] = __builtin_amdgcn_mfma_f32_16x16x32_bf16(ak1, bq[i][1], sa[j][i], 0, 0, 0);
      }
    }
    __builtin_amdgcn_s_setprio(0);
#pragma unroll
    for (int i = 0; i < 2; ++i) {
      float pmaxr = -3.0e38f;
#pragma unroll
      for (int j = 0; j < 4; ++j)
#pragma unroll
        for (int r = 0; r < 4; ++r) pmaxr = fmaxf(pmaxr, sa[j][i][r]);
      if (__any(fmaf(pmaxr, SC2, -m[i]) > THR)) {        // cold on sane logits
        float px = fmaxf(pmaxr, __shfl_xor(pmaxr, 16, 64));
        px = fmaxf(px, __shfl_xor(px, 32, 64));
        float mnew = fmaxf(m[i], px * SC2);
        float corr = __builtin_amdgcn_exp2f(m[i] - mnew);
        m[i] = mnew; l[i] *= corr;
        float cr[4];
#pragma unroll
        for (int r = 0; r < 4; ++r) cr[r] = __shfl(corr, lg * 4 + r, 64);
#pragma unroll
        for (int dj = 0; dj < 4; ++dj)
#pragma unroll
          for (int r = 0; r < 4; ++r) accO[i][dj][r] *= cr[r];
      }
      float p[4][4];
      float ts = 0.f;
#pragma unroll
      for (int j = 0; j < 4; ++j)
#pragma unroll
        for (int r = 0; r < 4; ++r) {
          p[j][r] = __builtin_amdgcn_exp2f(fmaf(sa[j][i][r], SC2, -m[i]));
          ts += p[j][r];
        }
      l[i] += ts;                                        // NO cross-lane reduce here
#pragma unroll
      for (int j = 0; j < 4; ++j) {
        uint2 pw;
        pw.x = packbf(p[j][0], p[j][1]);
        pw.y = packbf(p[j][2], p[j][3]);
        *(uint2*)(pwr[j] + i * 2048) = pw;
      }
    }
    bf16x8 pa[2][2];
#pragma unroll
    for (int i = 0; i < 2; ++i) {
      pa[i][0] = *(const bf16x8*)(paA + i * 2048);
      pa[i][1] = *(const bf16x8*)(paB + i * 2048);
    }
    __builtin_amdgcn_s_setprio(1);
#pragma unroll
    for (int dj = 0; dj < 4; ++dj) {
      bf16x8 bv0 = *(const bf16x8*)(vrA + dj * 2048);
      bf16x8 bv1 = *(const bf16x8*)(vrB + dj * 2048);
#pragma unroll
      for (int i = 0; i < 2; ++i) {
        accO[i][dj] = __builtin_amdgcn_mfma_f32_16x16x32_bf16(pa[i][0], bv0, accO[i][dj], 0, 0, 0);
        accO[i][dj] = __builtin_amdgcn_mfma_f32_16x16x32_bf16(pa[i][1], bv1, accO[i][dj], 0, 0, 0);
      }
    }
    __builtin_amdgcn_s_setprio(0);
  };

  for (int tt = 0; tt < 16; ++tt) {
    __syncthreads();                                 // buf0 ready; buf1 free
    stageTo(kd0_b1, kd1_b1, vd0_b1, vd1_b1);
    body(krA0, krB0, vrA0, vrB0);
    __syncthreads();                                 // buf1 ready; buf0 free
    if (tt < 15) stageTo(kd0_b0, kd1_b0, vd0_b0, vd1_b0);
    body(krA1, krB1, vrA1, vrB1);
  }

  // ---- epilogue: reduce partial l, then normalize
#pragma unroll
  for (int i = 0; i < 2; ++i) {
    float lt = l[i];
    lt += __shfl_xor(lt, 16, 64);
    lt += __shfl_xor(lt, 32, 64);
    float linv[4];
#pragma unroll
    for (int r = 0; r < 4; ++r) linv[r] = 1.0f / __shfl(lt, lg * 4 + r, 64);
#pragma unroll
    for (int dj = 0; dj < 4; ++dj)
#pragma unroll
      for (int r = 0; r < 4; ++r)
        AO[(size_t)(b * Ss + q0 + i * 16 + lg * 4 + r) * DMODEL + h * 64 + dj * 16 + l15] =
            f2bf(accO[i][dj][r] * linv[r]);
  }
}

// ---------------------------------------------------------------- launch
extern "C" void kernel_launch(void* const* d_in, const int* in_sizes, int n_in,
                              void* d_out, int out_size, void* d_ws, size_t ws_size,
                              hipStream_t stream) {
  const float* x      = (const float*)d_in[0];
  const float* Wdq    = (const float*)d_in[1];  const float* Wdq_b  = (const float*)d_in[2];
  const float* Wuq    = (const float*)d_in[3];  const float* Wuq_b  = (const float*)d_in[4];
  const float* Wqr    = (const float*)d_in[5];  const float* Wqr_b  = (const float*)d_in[6];
  const float* Wkr    = (const float*)d_in[7];  const float* Wkr_b  = (const float*)d_in[8];
  const float* Wdkv   = (const float*)d_in[9];  const float* Wdkv_b = (const float*)d_in[10];
  const float* Wuk    = (const float*)d_in[11]; const float* Wuk_b  = (const float*)d_in[12];
  const float* Wuv    = (const float*)d_in[13]; const float* Wuv_b  = (const float*)d_in[14];
  const float* Wo     = (const float*)d_in[15]; const float* Wo_b   = (const float*)d_in[16];

  // ---- workspace ----
  char* ws = (char*)d_ws;
  size_t off = 0;
  bf16* WdqT   = (bf16*)(ws + off); off += (size_t)512  * 1024 * 2;
  bf16* WdkvT  = (bf16*)(ws + off); off += (size_t)512  * 1024 * 2;
  bf16* WuqqrT = (bf16*)(ws + off); off += (size_t)1024 * 512  * 2;   // (Wuq+Wqr)^T
  bf16* WukT   = (bf16*)(ws + off); off += (size_t)1024 * 512  * 2;
  bf16* WuvT   = (bf16*)(ws + off); off += (size_t)1024 * 512  * 2;
  bf16* WkrT   = (bf16*)(ws + off); off += (size_t)1024 * 1024 * 2;
  bf16* WoT    = (bf16*)(ws + off); off += (size_t)1024 * 1024 * 2;
  bf16* x_bf   = (bf16*)(ws + off); off += (size_t)NTOK * 1024 * 2;
  bf16* ct     = (bf16*)(ws + off); off += (size_t)NTOK * 1024 * 2;   // [ct_q | ct_kv]
  bf16* Ga     = (bf16*)(ws + off); off += (size_t)NTOK * 1024 * 2;   // Qsum, later AO
  bf16* VTr    = (bf16*)(ws + off); off += (size_t)NTOK * 1024 * 2;
  float* qsum_b= (float*)(ws + off); off += 1024 * 4;
  bf16* Kn     = (bf16*)d_out + (size_t)NTOK * DMODEL; // Kr, then final K (in-place add)
  bf16* AO     = Ga;
  (void)ws_size; (void)in_sizes; (void)n_in; (void)out_size;

  // ---- merged transpose(+add) + x convert + qsum_b ----
  TransPack tp = {{
    { Wdq,  0,   WdqT,   1024, 512,  0    },
    { Wdkv, 0,   WdkvT,  1024, 512,  128  },
    { Wuq,  Wqr, WuqqrT, 512,  1024, 256  },
    { Wuk,  0,   WukT,   512,  1024, 384  },
    { Wuv,  0,   WuvT,   512,  1024, 512  },
    { Wkr,  0,   WkrT,   1024, 1024, 640  },
    { Wo,   0,   WoT,    1024, 1024, 896  },
    { 0, 0, 0, 0, 0, 1 << 30 },
  }};
  trans_conv_kernel<<<1152 + 4096 + 4, 256, 0, stream>>>(
      tp, x, x_bf, 1152, Wuq_b, Wqr_b, qsum_b, 1152 + 4096);

  // ---- batch A (512): down = x@[Wdq|Wdkv] -> ct ; Kr = x@Wkr + kr_b -> Kn ----
  GemmBatch ba = {{
    { x_bf, WdqT, Wdq_b, Wdkv_b, 0, ct, 1024, 1024, 1024, 1024, 512,     8, 0,       256, 0 },
    { x_bf, WkrT, Wkr_b, Wkr_b,  0, Kn, 1024, 1024, 1024, 1024, INT_MAX, 8, 256,     256, 0 },
    { 0, 0, 0, 0, 0, 0, 0, 0, 0, 0, 0, 1, INT_MAX, 1, 0 },
    { 0, 0, 0, 0, 0, 0, 0, 0, 0, 0, 0, 1, INT_MAX, 1, 0 },
  }};
  gemm_batch_kernel<<<512, 256, 0, stream>>>(ba);

  // ---- batch B (768): Qsum -> Ga ; K = upK + Kr(identity-rope, trig pair 0) in place ; V^T ----
  GemmBatch bb = {{
    { ct,       WuqqrT,   qsum_b, qsum_b, 0,  Ga,  1024, 512,  1024, 512, INT_MAX, 8,  0,       256, 0 },
    { ct + 512, WukT,     Wuk_b,  Wuk_b,  Kn, Kn,  1024, 512,  1024, 512, INT_MAX, 8,  256,     256, 0 },
    { WuvT,     ct + 512, Wuv_b,  Wuv_b,  0,  VTr, 512,  1024, NTOK, 512, INT_MAX, 32, 512,     256, 1 },
    { 0, 0, 0, 0, 0, 0, 0, 0, 0, 0, 0, 1, 1 << 30, 1, 0 },
  }};
  gemm_batch_kernel<<<768, 256, 0, stream>>>(bb);

  // ---- Q p=0 fixup (dims 0,1 of Qsum) ----
  fixup_q_kernel<<<NTOK / 4, 256, 0, stream>>>(ct, Wqr, Wqr_b, Ga);

  // ---- attention ----
  attn_kernel<<<dim3(32, 16), 256, 0, stream>>>(Ga, Kn, VTr, AO);

  // ---- output projection ----
  gemm_kernel_f32<<<dim3(16, 32), 256, 0, stream>>>(
      AO, 1024, WoT, 1024, Wo_b, (float*)d_out, 1024, 1024);
}

// Round 16
// 163.965 us; speedup vs baseline: 1.0761x; 1.0031x over previous
//
#include <hip/hip_runtime.h>
#include <hip/hip_bf16.h>
#include <math.h>
#include <limits.h>

typedef __hip_bfloat16 bf16;
typedef __bf16 bf16x8 __attribute__((ext_vector_type(8)));
typedef float  f32x4  __attribute__((ext_vector_type(4)));

#define DEVI __device__ __forceinline__

static constexpr int Bb     = 2;
static constexpr int Ss     = 2048;
static constexpr int DMODEL = 1024;
static constexpr int NTOK   = Bb * Ss;   // 4096

DEVI float bf2f(bf16 v) { return __bfloat162float(v); }
DEVI bf16  f2bf(float v) { return __float2bfloat16(v); }

DEVI unsigned int packbf(float lo, float hi) {
  union { bf16 b; unsigned short u; } a, c;
  a.b = f2bf(lo); c.b = f2bf(hi);
  return ((unsigned int)c.u << 16) | a.u;
}
DEVI float bfu2f(unsigned short u) {
  unsigned int x = (unsigned int)u << 16;
  float f; __builtin_memcpy(&f, &x, 4); return f;
}

DEVI void async_load16(const bf16* g, bf16* l) {
  __builtin_amdgcn_global_load_lds((const __attribute__((address_space(1))) void*)g,
                                   (__attribute__((address_space(3))) void*)l, 16, 0, 0);
}

// ---------------------------------------------------------------- transpose(+add) + convert + bias-sum
struct TransDesc { const float* src; const float* src2; bf16* dst; int R; int C; int tstart; };
struct TransPack { TransDesc d[8]; };

__global__ __launch_bounds__(256) void trans_conv_kernel(
    TransPack p, const float* __restrict__ cx, bf16* __restrict__ cxo, int tstartConv,
    const float* __restrict__ ba1, const float* __restrict__ ba2,
    float* __restrict__ bsum, int tstartB) {
  __shared__ bf16 tl[64][65];
  const int t = blockIdx.x;
  if (t >= tstartB) {
    const int j = (t - tstartB) * 256 + threadIdx.x;
    bsum[j] = ba1[j] + ba2[j];
    return;
  }
  if (t >= tstartConv) {
    const int idx = (t - tstartConv) * 256 + threadIdx.x;
    const float4 v = ((const float4*)cx)[idx];
    uint2 o; o.x = packbf(v.x, v.y); o.y = packbf(v.z, v.w);
    *(uint2*)&cxo[(size_t)idx * 4] = o;
    return;
  }
  int i = 0;
#pragma unroll
  for (int j = 1; j < 8; ++j) if (t >= p.d[j].tstart) i = j;
  const float* __restrict__ in  = p.d[i].src;
  const float* __restrict__ in2 = p.d[i].src2;
  bf16* __restrict__ out = p.d[i].dst;
  const int R = p.d[i].R, C = p.d[i].C;
  const int rel = t - p.d[i].tstart;
  const int tilesC = C >> 6;
  const int r0 = (rel / tilesC) * 64, c0 = (rel % tilesC) * 64;
  const int tc = threadIdx.x & 63, tr = threadIdx.x >> 6;
#pragma unroll
  for (int q = 0; q < 16; ++q) {
    int r = tr + q * 4;
    float v = in[(size_t)(r0 + r) * C + c0 + tc];
    if (in2) v += in2[(size_t)(r0 + r) * C + c0 + tc];
    tl[r][tc] = f2bf(v);
  }
  __syncthreads();
#pragma unroll
  for (int q = 0; q < 16; ++q) {
    int r = tr + q * 4;
    out[(size_t)(c0 + r) * R + r0 + tc] = tl[tc][r];
  }
}

// ---------------------------------------------------------------- batched GEMM, 128x64 tiles
// (4 waves; wave w owns rows [w*32, w*32+32) x all 64 cols). XCD chunk-swizzle per desc.
struct GemmDesc {
  const bf16* A; const bf16* WT; const float* b1; const float* b2; const bf16* addm; bf16* C;
  int lda, ldb, ldc, K, bsplit, nTX, blkStart, nBlk, biasRow;
};
struct GemmBatch { GemmDesc d[4]; };

__global__ __launch_bounds__(256) void gemm_batch_kernel(GemmBatch gb) {
  const int t = blockIdx.x;
  int di = 0;
#pragma unroll
  for (int j = 1; j < 4; ++j) if (t >= gb.d[j].blkStart) di = j;
  const GemmDesc D = gb.d[di];
  int rel = t - D.blkStart;
  if ((D.nBlk & 7) == 0) rel = (rel & 7) * (D.nBlk >> 3) + (rel >> 3);  // XCD chunk-swizzle
  const int tileN = (rel % D.nTX) * 64;
  const int tileM = (rel / D.nTX) * 128;

  __shared__ bf16 ldsA[128 * 32];
  __shared__ bf16 ldsB[64 * 32];
  const int tid = threadIdx.x;
  const int lane = tid & 63;
  const int w = tid >> 6;
  const int l15 = lane & 15, lg = lane >> 4;
  const int lrow = lane >> 2;
  const int lcol = (lane & 3) * 8;

  f32x4 acc[2][4] = {};

  for (int k0 = 0; k0 < D.K; k0 += 32) {
    async_load16(D.A  + (size_t)(tileM + w * 32 +      lrow) * D.lda + k0 + lcol, &ldsA[(w * 32) * 32]);
    async_load16(D.A  + (size_t)(tileM + w * 32 + 16 + lrow) * D.lda + k0 + lcol, &ldsA[(w * 32 + 16) * 32]);
    async_load16(D.WT + (size_t)(tileN + w * 16 + lrow) * D.ldb + k0 + lcol, &ldsB[(w * 16) * 32]);
    __syncthreads();

    bf16x8 af[2], bfr[4];
#pragma unroll
    for (int i = 0; i < 2; ++i)
      af[i]  = *(const bf16x8*)&ldsA[(w * 32 + i * 16 + l15) * 32 + lg * 8];
#pragma unroll
    for (int j = 0; j < 4; ++j)
      bfr[j] = *(const bf16x8*)&ldsB[(j * 16 + l15) * 32 + lg * 8];
#pragma unroll
    for (int i = 0; i < 2; ++i)
#pragma unroll
      for (int j = 0; j < 4; ++j)
        acc[i][j] = __builtin_amdgcn_mfma_f32_16x16x32_bf16(af[i], bfr[j], acc[i][j], 0, 0, 0);
    __syncthreads();
  }

  const int mbase = tileM + w * 32;
#pragma unroll
  for (int j = 0; j < 4; ++j) {
    int col = tileN + j * 16 + l15;
    float bvc = D.biasRow ? 0.0f : (col < D.bsplit ? D.b1[col] : D.b2[col - D.bsplit]);
    if (D.addm) {
      const int pcol = col >> 1;
      const bool odd = (col & 1) != 0;
#pragma unroll
      for (int i = 0; i < 2; ++i)
#pragma unroll
        for (int r = 0; r < 4; ++r) {
          int row = mbase + i * 16 + lg * 4 + r;
          unsigned int pr = *(const unsigned int*)((const char*)D.addm +
                              (size_t)row * D.ldc * 2 + (size_t)(col & ~1) * 2);
          float ke = bfu2f((unsigned short)(pr & 0xffff));
          float ko = bfu2f((unsigned short)(pr >> 16));
          float add;
          if (pcol == 0) {
            float rr = (float)(row & (Ss - 1)) * (1.0f / 512.0f);
            float c = cosf(rr), sn = sinf(rr);
            add = odd ? (ko * c + ke * sn) : (ke * c - ko * sn);
          } else {
            add = odd ? ko : ke;           // rope == identity for p>=1 at bf16
          }
          D.C[(size_t)row * D.ldc + col] = f2bf(acc[i][j][r] + bvc + add);
        }
    } else {
#pragma unroll
      for (int i = 0; i < 2; ++i)
#pragma unroll
        for (int r = 0; r < 4; ++r) {
          int row = mbase + i * 16 + lg * 4 + r;
          float bv = D.biasRow ? D.b1[row] : bvc;
          D.C[(size_t)row * D.ldc + col] = f2bf(acc[i][j][r] + bv);
        }
    }
  }
}

// ---------------------------------------------------------------- GEMM fp32-out (outproj), 128x64 tiles, XCD-swizzled
__global__ __launch_bounds__(256) void gemm_kernel_f32(
    const bf16* __restrict__ A, int lda,
    const bf16* __restrict__ WT, int ldb,
    const float* __restrict__ b1,
    float* __restrict__ Cout, int ldc, int K) {
  __shared__ bf16 ldsA[128 * 32];
  __shared__ bf16 ldsB[64 * 32];
  const int nBlk = gridDim.x * gridDim.y;
  int id = blockIdx.y * gridDim.x + blockIdx.x;
  id = (id & 7) * (nBlk >> 3) + (id >> 3);             // XCD chunk-swizzle
  const int tileM = (id / gridDim.x) * 128;
  const int tileN = (id % gridDim.x) * 64;
  const int tid = threadIdx.x;
  const int lane = tid & 63;
  const int w = tid >> 6;
  const int l15 = lane & 15, lg = lane >> 4;
  const int lrow = lane >> 2;
  const int lcol = (lane & 3) * 8;

  f32x4 acc[2][4] = {};

  for (int k0 = 0; k0 < K; k0 += 32) {
    async_load16(A  + (size_t)(tileM + w * 32 +      lrow) * lda + k0 + lcol, &ldsA[(w * 32) * 32]);
    async_load16(A  + (size_t)(tileM + w * 32 + 16 + lrow) * lda + k0 + lcol, &ldsA[(w * 32 + 16) * 32]);
    async_load16(WT + (size_t)(tileN + w * 16 + lrow) * ldb + k0 + lcol, &ldsB[(w * 16) * 32]);
    __syncthreads();

    bf16x8 af[2], bfr[4];
#pragma unroll
    for (int i = 0; i < 2; ++i)
      af[i]  = *(const bf16x8*)&ldsA[(w * 32 + i * 16 + l15) * 32 + lg * 8];
#pragma unroll
    for (int j = 0; j < 4; ++j)
      bfr[j] = *(const bf16x8*)&ldsB[(j * 16 + l15) * 32 + lg * 8];
#pragma unroll
    for (int i = 0; i < 2; ++i)
#pragma unroll
      for (int j = 0; j < 4; ++j)
        acc[i][j] = __builtin_amdgcn_mfma_f32_16x16x32_bf16(af[i], bfr[j], acc[i][j], 0, 0, 0);
    __syncthreads();
  }

#pragma unroll
  for (int j = 0; j < 4; ++j) {
    int col = tileN + j * 16 + l15;
    float bvc = b1[col];
#pragma unroll
    for (int i = 0; i < 2; ++i)
#pragma unroll
      for (int r = 0; r < 4; ++r) {
        int row = tileM + w * 32 + i * 16 + lg * 4 + r;
        Cout[(size_t)row * ldc + col] = acc[i][j][r] + bvc;
      }
  }
}

// ---------------------------------------------------------------- Q p=0 fixup
__global__ __launch_bounds__(256) void fixup_q_kernel(
    const bf16* __restrict__ ct, const float* __restrict__ Wqr,
    const float* __restrict__ Wqr_b, bf16* __restrict__ Q) {
  const int row = blockIdx.x * 4 + (threadIdx.x >> 6);
  const int lane = threadIdx.x & 63;
  const bf16* cr = ct + (size_t)row * 1024 + lane * 8;      // ct_q = cols [0,512)
  const float* wq = Wqr + (size_t)(lane * 8) * 1024;
  float q0 = 0.f, q1 = 0.f;
#pragma unroll
  for (int e = 0; e < 8; ++e) {
    float xv = bf2f(cr[e]);
    q0 = fmaf(xv, wq[e * 1024 + 0], q0);
    q1 = fmaf(xv, wq[e * 1024 + 1], q1);
  }
#pragma unroll
  for (int d = 32; d >= 1; d >>= 1) {
    q0 += __shfl_xor(q0, d, 64);
    q1 += __shfl_xor(q1, d, 64);
  }
  if (lane == 0) {
    const float Qr0 = q0 + Wqr_b[0], Qr1 = q1 + Wqr_b[1];
    const float rr = (float)(row & (Ss - 1)) * (1.0f / 512.0f);
    const float cm1 = cosf(rr) - 1.0f, sn = sinf(rr);
    const size_t base = (size_t)row * DMODEL;
    Q[base]     = f2bf(bf2f(Q[base])     + Qr0 * cm1 - Qr1 * sn);
    Q[base + 1] = f2bf(bf2f(Q[base + 1]) + Qr1 * cm1 + Qr0 * sn);
  }
}

// ---------------------------------------------------------------- attention v7 (unchanged, round-13/15)
__global__ __launch_bounds__(256) void attn_kernel(
    const bf16* __restrict__ Qm, const bf16* __restrict__ Kn,
    const bf16* __restrict__ VT, bf16* __restrict__ AO) {
  const int bh = blockIdx.x, qt = blockIdx.y;   // bh%8 == XCD -> K/V stays in one L2
  const int b = bh >> 4, h = bh & 15;
  const int tid = threadIdx.x, lane = tid & 63, w = tid >> 6;
  const int q0 = qt * 128 + w * 32;
  const int l15 = lane & 15, lg = lane >> 4;
  const float SC2 = 0.044736075f;    // (1/sqrt(1040)) * log2(e)
  const float THR = 11.5415603f;     // 8 * log2(e)

  __shared__ bf16 ldsK[2][64 * 64];
  __shared__ bf16 ldsV[2][64 * 64];
  __shared__ bf16 ldsP[4][32 * 64];

  const bf16* Kg = Kn + (size_t)(b * Ss) * DMODEL + h * 64;
  const bf16* Vg = VT + (size_t)(h * 64) * NTOK + b * Ss;

  const int r0 = tid >> 3;
  const int srcb = ((tid & 7) * 16) ^ ((r0 & 7) << 4);
  const char* kS0 = (const char*)(Kg + (size_t)r0 * DMODEL) + srcb;
  const char* kS1 = (const char*)(Kg + (size_t)(32 + r0) * DMODEL) + srcb;
  const char* vS0 = (const char*)(Vg + (size_t)r0 * NTOK) + srcb;
  const char* vS1 = (const char*)(Vg + (size_t)(32 + r0) * NTOK) + srcb;
  const ptrdiff_t kAdv = (ptrdiff_t)64 * DMODEL * 2;
  const ptrdiff_t vAdv = 128;

  bf16* kd0_b0 = &ldsK[0][w * 512]; bf16* kd1_b0 = &ldsK[0][2048 + w * 512];
  bf16* kd0_b1 = &ldsK[1][w * 512]; bf16* kd1_b1 = &ldsK[1][2048 + w * 512];
  bf16* vd0_b0 = &ldsV[0][w * 512]; bf16* vd1_b0 = &ldsV[0][2048 + w * 512];
  bf16* vd0_b1 = &ldsV[1][w * 512]; bf16* vd1_b1 = &ldsV[1][2048 + w * 512];

  auto stageTo = [&](bf16* kd0, bf16* kd1, bf16* vd0, bf16* vd1) {
    async_load16((const bf16*)kS0, kd0);
    async_load16((const bf16*)kS1, kd1);
    async_load16((const bf16*)vS0, vd0);
    async_load16((const bf16*)vS1, vd1);
    kS0 += kAdv; kS1 += kAdv; vS0 += vAdv; vS1 += vAdv;
  };

  stageTo(kd0_b0, kd1_b0, vd0_b0, vd1_b0);   // tile 0 in flight while Q loads

  const int kswz = (l15 & 7) << 4;
  const int xA = (lg * 16) ^ kswz;
  const int xB = (64 + lg * 16) ^ kswz;
  const char* krA0 = (const char*)&ldsK[0][0] + l15 * 128 + xA;
  const char* krB0 = (const char*)&ldsK[0][0] + l15 * 128 + xB;
  const char* krA1 = (const char*)&ldsK[1][0] + l15 * 128 + xA;
  const char* krB1 = (const char*)&ldsK[1][0] + l15 * 128 + xB;
  const char* vrA0 = (const char*)&ldsV[0][0] + l15 * 128 + xA;
  const char* vrB0 = (const char*)&ldsV[0][0] + l15 * 128 + xB;
  const char* vrA1 = (const char*)&ldsV[1][0] + l15 * 128 + xA;
  const char* vrB1 = (const char*)&ldsV[1][0] + l15 * 128 + xB;

  char* Pw = (char*)&ldsP[w][0];
  char* pwr[4];
#pragma unroll
  for (int j = 0; j < 4; ++j) {
    const int chunk = (j * 2 + (lg >> 1)) ^ (l15 & 7);
    pwr[j] = Pw + l15 * 128 + chunk * 16 + (lg & 1) * 8;
  }
  const char* paA = Pw + l15 * 128 + xA;
  const char* paB = Pw + l15 * 128 + xB;

  bf16x8 bq[2][2];
#pragma unroll
  for (int i = 0; i < 2; ++i) {
    const size_t rowoff = (size_t)(b * Ss + q0 + i * 16 + l15) * DMODEL + h * 64;
    bq[i][0] = *(const bf16x8*)&Qm[rowoff + lg * 8];
    bq[i][1] = *(const bf16x8*)&Qm[rowoff + 32 + lg * 8];
  }

  float m[2] = { 0.0f, 0.0f }, l[2] = { 0.0f, 0.0f };   // l = per-lane partial
  f32x4 accO[2][4] = {};

  auto body = [&](const char* krA, const char* krB, const char* vrA, const char* vrB) {
    f32x4 sa[4][2] = {};
    __builtin_amdgcn_s_setprio(1);
#pragma unroll
    for (int j = 0; j < 4; ++j) {
      bf16x8 ak0 = *(const bf16x8*)(krA + j * 2048);
      bf16x8 ak1 = *(const bf16x8*)(krB + j * 2048);
#pragma unroll
      for (int i = 0; i < 2; ++i) {
        sa[j][i] = __builtin_amdgcn_mfma_f32_16x16x32_bf16(ak0, bq[i][0], sa[j][i], 0, 0, 0);
        sa[j][i] = __builtin_amdgcn_mfma_f32_16x16x32_bf16(ak1, bq[i][1], sa[j][i], 0, 0, 0);
      }
    }
    __builtin_amdgcn_s_setprio(0);
#pragma unroll
    for (int i = 0; i < 2; ++i) {
      float pmaxr = -3.0e38f;
#pragma unroll
      for (int j = 0; j < 4; ++j)
#pragma unroll
        for (int r = 0; r < 4; ++r) pmaxr = fmaxf(pmaxr, sa[j][i][r]);
      if (__any(fmaf(pmaxr, SC2, -m[i]) > THR)) {        // cold on sane logits
        float px = fmaxf(pmaxr, __shfl_xor(pmaxr, 16, 64));
        px = fmaxf(px, __shfl_xor(px, 32, 64));
        float mnew = fmaxf(m[i], px * SC2);
        float corr = __builtin_amdgcn_exp2f(m[i] - mnew);
        m[i] = mnew; l[i] *= corr;
        float cr[4];
#pragma unroll
        for (int r = 0; r < 4; ++r) cr[r] = __shfl(corr, lg * 4 + r, 64);
#pragma unroll
        for (int dj = 0; dj < 4; ++dj)
#pragma unroll
          for (int r = 0; r < 4; ++r) accO[i][dj][r] *= cr[r];
      }
      float p[4][4];
      float ts = 0.f;
#pragma unroll
      for (int j = 0; j < 4; ++j)
#pragma unroll
        for (int r = 0; r < 4; ++r) {
          p[j][r] = __builtin_amdgcn_exp2f(fmaf(sa[j][i][r], SC2, -m[i]));
          ts += p[j][r];
        }
      l[i] += ts;                                        // NO cross-lane reduce here
#pragma unroll
      for (int j = 0; j < 4; ++j) {
        uint2 pw;
        pw.x = packbf(p[j][0], p[j][1]);
        pw.y = packbf(p[j][2], p[j][3]);
        *(uint2*)(pwr[j] + i * 2048) = pw;
      }
    }
    bf16x8 pa[2][2];
#pragma unroll
    for (int i = 0; i < 2; ++i) {
      pa[i][0] = *(const bf16x8*)(paA + i * 2048);
      pa[i][1] = *(const bf16x8*)(paB + i * 2048);
    }
    __builtin_amdgcn_s_setprio(1);
#pragma unroll
    for (int dj = 0; dj < 4; ++dj) {
      bf16x8 bv0 = *(const bf16x8*)(vrA + dj * 2048);
      bf16x8 bv1 = *(const bf16x8*)(vrB + dj * 2048);
#pragma unroll
      for (int i = 0; i < 2; ++i) {
        accO[i][dj] = __builtin_amdgcn_mfma_f32_16x16x32_bf16(pa[i][0], bv0, accO[i][dj], 0, 0, 0);
        accO[i][dj] = __builtin_amdgcn_mfma_f32_16x16x32_bf16(pa[i][1], bv1, accO[i][dj], 0, 0, 0);
      }
    }
    __builtin_amdgcn_s_setprio(0);
  };

  for (int tt = 0; tt < 16; ++tt) {
    __syncthreads();                                 // buf0 ready; buf1 free
    stageTo(kd0_b1, kd1_b1, vd0_b1, vd1_b1);
    body(krA0, krB0, vrA0, vrB0);
    __syncthreads();                                 // buf1 ready; buf0 free
    if (tt < 15) stageTo(kd0_b0, kd1_b0, vd0_b0, vd1_b0);
    body(krA1, krB1, vrA1, vrB1);
  }

  // ---- epilogue: reduce partial l, then normalize
#pragma unroll
  for (int i = 0; i < 2; ++i) {
    float lt = l[i];
    lt += __shfl_xor(lt, 16, 64);
    lt += __shfl_xor(lt, 32, 64);
    float linv[4];
#pragma unroll
    for (int r = 0; r < 4; ++r) linv[r] = 1.0f / __shfl(lt, lg * 4 + r, 64);
#pragma unroll
    for (int dj = 0; dj < 4; ++dj)
#pragma unroll
      for (int r = 0; r < 4; ++r)
        AO[(size_t)(b * Ss + q0 + i * 16 + lg * 4 + r) * DMODEL + h * 64 + dj * 16 + l15] =
            f2bf(accO[i][dj][r] * linv[r]);
  }
}

// ---------------------------------------------------------------- launch
extern "C" void kernel_launch(void* const* d_in, const int* in_sizes, int n_in,
                              void* d_out, int out_size, void* d_ws, size_t ws_size,
                              hipStream_t stream) {
  const float* x      = (const float*)d_in[0];
  const float* Wdq    = (const float*)d_in[1];  const float* Wdq_b  = (const float*)d_in[2];
  const float* Wuq    = (const float*)d_in[3];  const float* Wuq_b  = (const float*)d_in[4];
  const float* Wqr    = (const float*)d_in[5];  const float* Wqr_b  = (const float*)d_in[6];
  const float* Wkr    = (const float*)d_in[7];  const float* Wkr_b  = (const float*)d_in[8];
  const float* Wdkv   = (const float*)d_in[9];  const float* Wdkv_b = (const float*)d_in[10];
  const float* Wuk    = (const float*)d_in[11]; const float* Wuk_b  = (const float*)d_in[12];
  const float* Wuv    = (const float*)d_in[13]; const float* Wuv_b  = (const float*)d_in[14];
  const float* Wo     = (const float*)d_in[15]; const float* Wo_b   = (const float*)d_in[16];

  // ---- workspace ----
  char* ws = (char*)d_ws;
  size_t off = 0;
  bf16* WdqT   = (bf16*)(ws + off); off += (size_t)512  * 1024 * 2;
  bf16* WdkvT  = (bf16*)(ws + off); off += (size_t)512  * 1024 * 2;
  bf16* WuqqrT = (bf16*)(ws + off); off += (size_t)1024 * 512  * 2;   // (Wuq+Wqr)^T
  bf16* WukT   = (bf16*)(ws + off); off += (size_t)1024 * 512  * 2;
  bf16* WuvT   = (bf16*)(ws + off); off += (size_t)1024 * 512  * 2;
  bf16* WkrT   = (bf16*)(ws + off); off += (size_t)1024 * 1024 * 2;
  bf16* WoT    = (bf16*)(ws + off); off += (size_t)1024 * 1024 * 2;
  bf16* x_bf   = (bf16*)(ws + off); off += (size_t)NTOK * 1024 * 2;
  bf16* ct     = (bf16*)(ws + off); off += (size_t)NTOK * 1024 * 2;   // [ct_q | ct_kv]
  bf16* Ga     = (bf16*)(ws + off); off += (size_t)NTOK * 1024 * 2;   // Qsum, later AO
  bf16* VTr    = (bf16*)(ws + off); off += (size_t)NTOK * 1024 * 2;
  float* qsum_b= (float*)(ws + off); off += 1024 * 4;
  bf16* Kn     = (bf16*)d_out + (size_t)NTOK * DMODEL; // Kr, then final K (in-place add)
  bf16* AO     = Ga;
  (void)ws_size; (void)in_sizes; (void)n_in; (void)out_size;

  // ---- merged transpose(+add) + x convert + qsum_b ----
  TransPack tp = {{
    { Wdq,  0,   WdqT,   1024, 512,  0    },
    { Wdkv, 0,   WdkvT,  1024, 512,  128  },
    { Wuq,  Wqr, WuqqrT, 512,  1024, 256  },
    { Wuk,  0,   WukT,   512,  1024, 384  },
    { Wuv,  0,   WuvT,   512,  1024, 512  },
    { Wkr,  0,   WkrT,   1024, 1024, 640  },
    { Wo,   0,   WoT,    1024, 1024, 896  },
    { 0, 0, 0, 0, 0, 1 << 30 },
  }};
  trans_conv_kernel<<<1152 + 4096 + 4, 256, 0, stream>>>(
      tp, x, x_bf, 1152, Wuq_b, Wqr_b, qsum_b, 1152 + 4096);

  // ---- batch A (1024 blocks, 128x64): down -> ct ; Kr -> Kn ----
  GemmBatch ba = {{
    { x_bf, WdqT, Wdq_b, Wdkv_b, 0, ct, 1024, 1024, 1024, 1024, 512,     16, 0,       512, 0 },
    { x_bf, WkrT, Wkr_b, Wkr_b,  0, Kn, 1024, 1024, 1024, 1024, INT_MAX, 16, 512,     512, 0 },
    { 0, 0, 0, 0, 0, 0, 0, 0, 0, 0, 0, 1, INT_MAX, 1, 0 },
    { 0, 0, 0, 0, 0, 0, 0, 0, 0, 0, 0, 1, INT_MAX, 1, 0 },
  }};
  gemm_batch_kernel<<<1024, 256, 0, stream>>>(ba);

  // ---- batch B (1536 blocks, 128x64): Qsum -> Ga ; K = upK + Kr(identity-rope) in place ; V^T ----
  GemmBatch bb = {{
    { ct,       WuqqrT,   qsum_b, qsum_b, 0,  Ga,  1024, 512,  1024, 512, INT_MAX, 16, 0,       512, 0 },
    { ct + 512, WukT,     Wuk_b,  Wuk_b,  Kn, Kn,  1024, 512,  1024, 512, INT_MAX, 16, 512,     512, 0 },
    { WuvT,     ct + 512, Wuv_b,  Wuv_b,  0,  VTr, 512,  1024, NTOK, 512, INT_MAX, 64, 1024,    512, 1 },
    { 0, 0, 0, 0, 0, 0, 0, 0, 0, 0, 0, 1, 1 << 30, 1, 0 },
  }};
  gemm_batch_kernel<<<1536, 256, 0, stream>>>(bb);

  // ---- Q p=0 fixup (dims 0,1 of Qsum) ----
  fixup_q_kernel<<<NTOK / 4, 256, 0, stream>>>(ct, Wqr, Wqr_b, Ga);

  // ---- attention ----
  attn_kernel<<<dim3(32, 16), 256, 0, stream>>>(Ga, Kn, VTr, AO);

  // ---- output projection ----
  gemm_kernel_f32<<<dim3(16, 32), 256, 0, stream>>>(
      AO, 1024, WoT, 1024, Wo_b, (float*)d_out, 1024, 1024);
}